// Round 4
// baseline (677.746 us; speedup 1.0000x reference)
//
#include <hip/hip_runtime.h>
#include <hip/hip_bf16.h>

// Problem constants (from reference setup_inputs)
#define BB 4
#define MM 16384
#define NN 32768
#define KK 16
#define ROWS (BB * NN)   // 131072
#define OUTW 131         // 3 coords + 64 + 64
#define RPW 16           // rows per wave
#define A_BLOCKS (ROWS / (RPW * 4))  // 2048 blocks of 4 waves
#define NSLOT 16         // accumulator slot copies (atomic contention /16)
#define NEG_INF -3.402823466e38f

// ws layout (floats):
//   [0 : NSLOT*256)            per-slot partial sums: slot s at s*256:
//        +0 sum1, +64 sq1, +128 sum2, +192 sq2
//   [4096 : 4224)              a  (a1[64] | a2[64])
//   [4224 : 4352)              c  (c1[64] | c2[64])

// ---------------------------------------------------------------------------
// Kernel 1: gather + max-pool + (pooled @ W1 + b1) -> out[..., 3:67] (unnorm)
//           + coords -> out[..., 0:3], + per-channel sum/sumsq partials.
// One wave per row-group; lane = channel. 4-row batching: one coalesced idx
// load (64 lanes = 4 rows x 16 idx), 64 gather loads in flight, 4 independent
// dot accumulators. XCD swizzle keeps each XCD's gather set = one batch
// (proven: FETCH 211->66 MB).
// ---------------------------------------------------------------------------
__global__ __launch_bounds__(256, 5) void k_pool_proj(
    const float* __restrict__ cf, const int* __restrict__ idxs,
    const float* __restrict__ scoord,
    const float* __restrict__ W1, const float* __restrict__ b1,
    float* __restrict__ out, float* __restrict__ acc)
{
    __shared__ float pool[4][4][64];   // [wave][row][chan]
    __shared__ float lsum[64], lsq[64];
    const int lane = threadIdx.x & 63;
    const int wv   = threadIdx.x >> 6;
    if (threadIdx.x < 64) { lsum[threadIdx.x] = 0.f; lsq[threadIdx.x] = 0.f; }
    __syncthreads();

    // XCD-aware decomposition: batch b -> XCD pair {2b, 2b+1}
    const int xcd   = blockIdx.x & 7;
    const int batch = xcd >> 1;                              // 0..3
    const int blkIB = ((blockIdx.x >> 3) << 1) | (xcd & 1);  // 0..511
    const int gw    = blkIB * 4 + wv;                        // 0..2047
    const int rbase = (batch << 15) + gw * RPW;
    const float* __restrict__ cfb = cf + ((size_t)batch << 20);  // batch*M*64

    float w[64];
#pragma unroll
    for (int c = 0; c < 64; ++c) w[c] = W1[c * 64 + lane];
    const float bias = b1[lane];

    float psum = 0.f, psq = 0.f;
#pragma unroll 1
    for (int it = 0; it < RPW / 4; ++it) {
        const int r4 = rbase + it * 4;
        // one coalesced load: lane -> (row = lane>>4, k = lane&15)
        const int mi = idxs[r4 * KK + lane];
        float pm0 = NEG_INF, pm1 = NEG_INF, pm2 = NEG_INF, pm3 = NEG_INF;
#pragma unroll
        for (int k = 0; k < KK; ++k) {
            const int m0 = __shfl(mi, k);
            const int m1 = __shfl(mi, 16 + k);
            const int m2 = __shfl(mi, 32 + k);
            const int m3 = __shfl(mi, 48 + k);
            pm0 = fmaxf(pm0, cfb[((size_t)m0 << 6) + lane]);
            pm1 = fmaxf(pm1, cfb[((size_t)m1 << 6) + lane]);
            pm2 = fmaxf(pm2, cfb[((size_t)m2 << 6) + lane]);
            pm3 = fmaxf(pm3, cfb[((size_t)m3 << 6) + lane]);
        }
        pool[wv][0][lane] = pm0;
        pool[wv][1][lane] = pm1;
        pool[wv][2][lane] = pm2;
        pool[wv][3][lane] = pm3;
        __builtin_amdgcn_wave_barrier();

        const float4* t0 = (const float4*)&pool[wv][0][0];
        const float4* t1 = (const float4*)&pool[wv][1][0];
        const float4* t2 = (const float4*)&pool[wv][2][0];
        const float4* t3 = (const float4*)&pool[wv][3][0];
        float yy0 = bias, yy1 = bias, yy2 = bias, yy3 = bias;
#pragma unroll
        for (int c4 = 0; c4 < 16; ++c4) {
            const float4 p0 = t0[c4], p1 = t1[c4], p2 = t2[c4], p3 = t3[c4];
            const float w0 = w[4*c4+0], w1v = w[4*c4+1], w2v = w[4*c4+2], w3v = w[4*c4+3];
            yy0 = fmaf(p0.x, w0, yy0); yy0 = fmaf(p0.y, w1v, yy0);
            yy0 = fmaf(p0.z, w2v, yy0); yy0 = fmaf(p0.w, w3v, yy0);
            yy1 = fmaf(p1.x, w0, yy1); yy1 = fmaf(p1.y, w1v, yy1);
            yy1 = fmaf(p1.z, w2v, yy1); yy1 = fmaf(p1.w, w3v, yy1);
            yy2 = fmaf(p2.x, w0, yy2); yy2 = fmaf(p2.y, w1v, yy2);
            yy2 = fmaf(p2.z, w2v, yy2); yy2 = fmaf(p2.w, w3v, yy2);
            yy3 = fmaf(p3.x, w0, yy3); yy3 = fmaf(p3.y, w1v, yy3);
            yy3 = fmaf(p3.z, w2v, yy3); yy3 = fmaf(p3.w, w3v, yy3);
        }
        __builtin_amdgcn_wave_barrier();

        out[(size_t)(r4 + 0) * OUTW + 3 + lane] = yy0;
        out[(size_t)(r4 + 1) * OUTW + 3 + lane] = yy1;
        out[(size_t)(r4 + 2) * OUTW + 3 + lane] = yy2;
        out[(size_t)(r4 + 3) * OUTW + 3 + lane] = yy3;
        if (lane < 3) {
#pragma unroll
            for (int ri = 0; ri < 4; ++ri)
                out[(size_t)(r4 + ri) * OUTW + lane] = scoord[(r4 + ri) * 3 + lane];
        }
        psum += yy0 + yy1 + yy2 + yy3;
        psq  += yy0*yy0 + yy1*yy1 + yy2*yy2 + yy3*yy3;
    }
    atomicAdd(&lsum[lane], psum);
    atomicAdd(&lsq[lane], psq);
    __syncthreads();
    if (threadIdx.x < 64) {
        float* slot = acc + (blockIdx.x & (NSLOT - 1)) * 256;
        atomicAdd(&slot[threadIdx.x],      lsum[threadIdx.x]);
        atomicAdd(&slot[64 + threadIdx.x], lsq[threadIdx.x]);
    }
}

// ---------------------------------------------------------------------------
// Kernel 2: (skip_feat @ W2 + b2) -> out[..., 67:131] (unnorm) + stats.
// 4-row batching: ONE global_load_dwordx4 per lane covers 4 full rows
// (sf rows are contiguous: 4 x 64 = 256 floats = 64 lanes x float4).
// ---------------------------------------------------------------------------
__global__ __launch_bounds__(256, 5) void k_skip_proj(
    const float* __restrict__ sf,
    const float* __restrict__ W2, const float* __restrict__ b2,
    float* __restrict__ out, float* __restrict__ acc)
{
    __shared__ float tile[4][4][64];
    __shared__ float lsum[64], lsq[64];
    const int lane = threadIdx.x & 63;
    const int wv   = threadIdx.x >> 6;
    if (threadIdx.x < 64) { lsum[threadIdx.x] = 0.f; lsq[threadIdx.x] = 0.f; }
    __syncthreads();

    float w[64];
#pragma unroll
    for (int c = 0; c < 64; ++c) w[c] = W2[c * 64 + lane];
    const float bias = b2[lane];
    const float4* __restrict__ sf4 = (const float4*)sf;

    const int gw    = blockIdx.x * 4 + wv;
    const int rbase = gw * RPW;

    float psum = 0.f, psq = 0.f;
#pragma unroll 1
    for (int it = 0; it < RPW / 4; ++it) {
        const int r4 = rbase + it * 4;
        // 4 rows in one vector load: element lane of sf4[r4*16 ..]
        const float4 v = sf4[r4 * 16 + lane];
        ((float4*)&tile[wv][0][0])[lane] = v;
        __builtin_amdgcn_wave_barrier();

        const float4* t0 = (const float4*)&tile[wv][0][0];
        const float4* t1 = (const float4*)&tile[wv][1][0];
        const float4* t2 = (const float4*)&tile[wv][2][0];
        const float4* t3 = (const float4*)&tile[wv][3][0];
        float yy0 = bias, yy1 = bias, yy2 = bias, yy3 = bias;
#pragma unroll
        for (int c4 = 0; c4 < 16; ++c4) {
            const float4 p0 = t0[c4], p1 = t1[c4], p2 = t2[c4], p3 = t3[c4];
            const float w0 = w[4*c4+0], w1v = w[4*c4+1], w2v = w[4*c4+2], w3v = w[4*c4+3];
            yy0 = fmaf(p0.x, w0, yy0); yy0 = fmaf(p0.y, w1v, yy0);
            yy0 = fmaf(p0.z, w2v, yy0); yy0 = fmaf(p0.w, w3v, yy0);
            yy1 = fmaf(p1.x, w0, yy1); yy1 = fmaf(p1.y, w1v, yy1);
            yy1 = fmaf(p1.z, w2v, yy1); yy1 = fmaf(p1.w, w3v, yy1);
            yy2 = fmaf(p2.x, w0, yy2); yy2 = fmaf(p2.y, w1v, yy2);
            yy2 = fmaf(p2.z, w2v, yy2); yy2 = fmaf(p2.w, w3v, yy2);
            yy3 = fmaf(p3.x, w0, yy3); yy3 = fmaf(p3.y, w1v, yy3);
            yy3 = fmaf(p3.z, w2v, yy3); yy3 = fmaf(p3.w, w3v, yy3);
        }
        __builtin_amdgcn_wave_barrier();

        out[(size_t)(r4 + 0) * OUTW + 67 + lane] = yy0;
        out[(size_t)(r4 + 1) * OUTW + 67 + lane] = yy1;
        out[(size_t)(r4 + 2) * OUTW + 67 + lane] = yy2;
        out[(size_t)(r4 + 3) * OUTW + 67 + lane] = yy3;
        psum += yy0 + yy1 + yy2 + yy3;
        psq  += yy0*yy0 + yy1*yy1 + yy2*yy2 + yy3*yy3;
    }
    atomicAdd(&lsum[lane], psum);
    atomicAdd(&lsq[lane], psq);
    __syncthreads();
    if (threadIdx.x < 64) {
        float* slot = acc + (blockIdx.x & (NSLOT - 1)) * 256;
        atomicAdd(&slot[128 + threadIdx.x], lsum[threadIdx.x]);
        atomicAdd(&slot[192 + threadIdx.x], lsq[threadIdx.x]);
    }
}

// ---------------------------------------------------------------------------
// Fold NSLOT partial-sum slots -> affine params a = g*rsqrt(var+eps),
// c = beta - mu*a.  Writes a to ws[4096:4224], c to ws[4224:4352].
// ---------------------------------------------------------------------------
__global__ void k_stats(float* __restrict__ ws,
                        const float* __restrict__ g1, const float* __restrict__ be1,
                        const float* __restrict__ g2, const float* __restrict__ be2)
{
    const int o = threadIdx.x;  // 64 threads
    float s1 = 0.f, q1 = 0.f, s2 = 0.f, q2 = 0.f;
#pragma unroll
    for (int s = 0; s < NSLOT; ++s) {
        const float* p = ws + s * 256;
        s1 += p[o]; q1 += p[64 + o]; s2 += p[128 + o]; q2 += p[192 + o];
    }
    const float inv = 1.0f / (float)ROWS;
    const float m1 = s1 * inv;
    const float v1 = q1 * inv - m1 * m1;
    const float a1 = g1[o] * rsqrtf(v1 + 1e-5f);
    ws[4096 + o] = a1;
    ws[4224 + o] = be1[o] - m1 * a1;
    const float m2 = s2 * inv;
    const float v2 = q2 * inv - m2 * m2;
    const float a2 = g2[o] * rsqrtf(v2 + 1e-5f);
    ws[4096 + 64 + o] = a2;
    ws[4224 + 64 + o] = be2[o] - m2 * a2;
}

// ---------------------------------------------------------------------------
// In-place  out[r*131 + 3 + j] = relu(a[j]*y + c[j]),  j in [0,128)
// ---------------------------------------------------------------------------
__global__ __launch_bounds__(256) void k_finalize(float* __restrict__ out,
                                                  const float* __restrict__ ws)
{
    const size_t T  = (size_t)gridDim.x * blockDim.x;
    const size_t t0 = (size_t)blockIdx.x * blockDim.x + threadIdx.x;
#pragma unroll
    for (int i = 0; i < 4; ++i) {
        const size_t e = t0 + (size_t)i * T;       // e < ROWS*128
        const size_t r = e >> 7;
        const int    j = (int)(e & 127);
        const size_t ad = r * OUTW + 3 + j;
        const float v = out[ad];
        out[ad] = fmaxf(fmaf(v, ws[4096 + j], ws[4224 + j]), 0.f);
    }
}

// ---------------------------------------------------------------------------
extern "C" void kernel_launch(void* const* d_in, const int* in_sizes, int n_in,
                              void* d_out, int out_size, void* d_ws, size_t ws_size,
                              hipStream_t stream)
{
    const float* cf     = (const float*)d_in[1];   // curr_feat (B,M,64)
    const float* scoord = (const float*)d_in[2];   // skip_coords (B,N,3)
    const float* sf     = (const float*)d_in[3];   // skip_feat (B,N,64)
    const int*   idxs   = (const int*)  d_in[4];   // upsampling_idxs (B,N,16)
    const float* W1     = (const float*)d_in[5];
    const float* b1     = (const float*)d_in[6];
    const float* g1     = (const float*)d_in[7];
    const float* be1    = (const float*)d_in[8];
    const float* W2     = (const float*)d_in[9];
    const float* b2     = (const float*)d_in[10];
    const float* g2     = (const float*)d_in[11];
    const float* be2    = (const float*)d_in[12];
    float* out = (float*)d_out;
    float* ws  = (float*)d_ws;

    hipMemsetAsync(ws, 0, NSLOT * 256 * sizeof(float), stream);
    k_pool_proj<<<A_BLOCKS, 256, 0, stream>>>(cf, idxs, scoord, W1, b1, out, ws);
    k_skip_proj<<<A_BLOCKS, 256, 0, stream>>>(sf, W2, b2, out, ws);
    k_stats<<<1, 64, 0, stream>>>(ws, g1, be1, g2, be2);
    // ROWS*128 = 16,777,216 elements; 16384 blocks * 256 threads * 4 elems
    k_finalize<<<16384, 256, 0, stream>>>(out, ws);
}

// Round 5
// 364.090 us; speedup vs baseline: 1.8615x; 1.8615x over previous
//
#include <hip/hip_runtime.h>
#include <hip/hip_bf16.h>

// Problem constants (from reference setup_inputs)
#define BB 4
#define MM 16384
#define NN 32768
#define KK 16
#define ROWS (BB * NN)   // 131072
#define OUTW 131         // 3 coords + 64 + 64
#define RPW 32           // rows per wave
#define A_BLOCKS (ROWS / (RPW * 4))  // 1024 blocks of 4 waves
#define NSLOT 16         // stats accumulator slot copies
#define NEG_INF -3.402823466e38f

// ws layout (floats): [0 : NSLOT*256) partial sums; slot s at s*256:
//    +0 sum1[64], +64 sq1[64], +128 sum2[64], +192 sq2[64]

// ---------------------------------------------------------------------------
// Kernel 1: gather + max-pool + (pooled @ W1 + b1) -> out[..., 3:67] (unnorm)
//           + coords -> out[..., 0:3], + per-channel sum/sumsq partials.
// One wave per row-group; lane = channel.
//  - XCD swizzle: batch b -> XCD pair {2b,2b+1} (proven: FETCH 211->66 MB).
//  - idx: ONE coalesced load per 4 rows (64 lanes = 4x16 idx) -> breaks the
//    per-row idx->gather serial chain (round-3's latency limiter).
//  - gathers issued 2 rows at a time = 32 in flight (round 4 proved 64 in
//    flight thrashes L2: FETCH 754 MB, VALUBusy 9.7%).
//  - tree max, 4 dots sharing each w/tile read.
// ---------------------------------------------------------------------------
__global__ __launch_bounds__(256) void k_pool_proj(
    const float* __restrict__ cf, const int* __restrict__ idxs,
    const float* __restrict__ scoord,
    const float* __restrict__ W1, const float* __restrict__ b1,
    float* __restrict__ out, float* __restrict__ acc)
{
    __shared__ float pool[4][4][64];   // [wave][row][chan]
    __shared__ float lsum[64], lsq[64];
    const int lane = threadIdx.x & 63;
    const int wv   = threadIdx.x >> 6;
    if (threadIdx.x < 64) { lsum[threadIdx.x] = 0.f; lsq[threadIdx.x] = 0.f; }
    __syncthreads();

    // XCD-aware decomposition: batch b -> XCD pair {2b, 2b+1}
    const int xcd   = blockIdx.x & 7;
    const int batch = xcd >> 1;                              // 0..3
    const int blkIB = ((blockIdx.x >> 3) << 1) | (xcd & 1);  // 0..255
    const int gw    = blkIB * 4 + wv;                        // 0..1023
    const int rbase = (batch << 15) + gw * RPW;
    const float* __restrict__ cfb = cf + ((size_t)batch << 20);  // batch*M*64

    float w[64];
#pragma unroll
    for (int c = 0; c < 64; ++c) w[c] = W1[c * 64 + lane];
    const float bias = b1[lane];

    float psum = 0.f, psq = 0.f;
#pragma unroll 1
    for (int it = 0; it < RPW / 4; ++it) {
        const int r4 = rbase + it * 4;
        // one coalesced idx load covers 4 rows (lane -> row=lane>>4, k=lane&15)
        const int mi = idxs[(size_t)r4 * KK + lane];

        float va[16], vb[16];
        // rows 0,1: 32 gathers in flight
#pragma unroll
        for (int k = 0; k < KK; ++k) {
            const int m = __shfl(mi, k);
            va[k] = cfb[((size_t)m << 6) + lane];
        }
#pragma unroll
        for (int k = 0; k < KK; ++k) {
            const int m = __shfl(mi, 16 + k);
            vb[k] = cfb[((size_t)m << 6) + lane];
        }
#pragma unroll
        for (int s = 8; s > 0; s >>= 1)
#pragma unroll
            for (int k = 0; k < s; ++k) {
                va[k] = fmaxf(va[k], va[k + s]);
                vb[k] = fmaxf(vb[k], vb[k + s]);
            }
        pool[wv][0][lane] = va[0];
        pool[wv][1][lane] = vb[0];
        // rows 2,3
#pragma unroll
        for (int k = 0; k < KK; ++k) {
            const int m = __shfl(mi, 32 + k);
            va[k] = cfb[((size_t)m << 6) + lane];
        }
#pragma unroll
        for (int k = 0; k < KK; ++k) {
            const int m = __shfl(mi, 48 + k);
            vb[k] = cfb[((size_t)m << 6) + lane];
        }
#pragma unroll
        for (int s = 8; s > 0; s >>= 1)
#pragma unroll
            for (int k = 0; k < s; ++k) {
                va[k] = fmaxf(va[k], va[k + s]);
                vb[k] = fmaxf(vb[k], vb[k + s]);
            }
        pool[wv][2][lane] = va[0];
        pool[wv][3][lane] = vb[0];
        __builtin_amdgcn_wave_barrier();

        const float4* t0 = (const float4*)&pool[wv][0][0];
        const float4* t1 = (const float4*)&pool[wv][1][0];
        const float4* t2 = (const float4*)&pool[wv][2][0];
        const float4* t3 = (const float4*)&pool[wv][3][0];
        float y0 = bias, y1 = bias, y2 = bias, y3 = bias;
#pragma unroll
        for (int c4 = 0; c4 < 16; ++c4) {
            const float4 p0 = t0[c4], p1 = t1[c4], p2 = t2[c4], p3 = t3[c4];
            const float wa = w[4*c4+0], wb = w[4*c4+1], wc = w[4*c4+2], wd = w[4*c4+3];
            y0 = fmaf(p0.x, wa, y0); y0 = fmaf(p0.y, wb, y0);
            y0 = fmaf(p0.z, wc, y0); y0 = fmaf(p0.w, wd, y0);
            y1 = fmaf(p1.x, wa, y1); y1 = fmaf(p1.y, wb, y1);
            y1 = fmaf(p1.z, wc, y1); y1 = fmaf(p1.w, wd, y1);
            y2 = fmaf(p2.x, wa, y2); y2 = fmaf(p2.y, wb, y2);
            y2 = fmaf(p2.z, wc, y2); y2 = fmaf(p2.w, wd, y2);
            y3 = fmaf(p3.x, wa, y3); y3 = fmaf(p3.y, wb, y3);
            y3 = fmaf(p3.z, wc, y3); y3 = fmaf(p3.w, wd, y3);
        }
        __builtin_amdgcn_wave_barrier();

        out[(size_t)(r4 + 0) * OUTW + 3 + lane] = y0;
        out[(size_t)(r4 + 1) * OUTW + 3 + lane] = y1;
        out[(size_t)(r4 + 2) * OUTW + 3 + lane] = y2;
        out[(size_t)(r4 + 3) * OUTW + 3 + lane] = y3;
        if (lane < 12) {   // 4 rows x 3 coords; scoord read is coalesced
            const int ri = lane / 3, cc = lane - ri * 3;
            out[(size_t)(r4 + ri) * OUTW + cc] = scoord[(size_t)r4 * 3 + lane];
        }
        psum += y0 + y1 + y2 + y3;
        psq  += y0*y0 + y1*y1 + y2*y2 + y3*y3;
    }
    atomicAdd(&lsum[lane], psum);
    atomicAdd(&lsq[lane], psq);
    __syncthreads();
    if (threadIdx.x < 64) {
        float* slot = acc + (blockIdx.x & (NSLOT - 1)) * 256;
        atomicAdd(&slot[threadIdx.x],      lsum[threadIdx.x]);
        atomicAdd(&slot[64 + threadIdx.x], lsq[threadIdx.x]);
    }
}

// ---------------------------------------------------------------------------
// Kernel 2: (skip_feat @ W2 + b2) -> out[..., 67:131] (unnorm) + stats.
// 4-row batching: ONE global_load_dwordx4 per lane covers 4 full rows.
// Pure streaming; no launch-bounds cap (round 4's (256,5) suspect removed).
// ---------------------------------------------------------------------------
__global__ __launch_bounds__(256) void k_skip_proj(
    const float* __restrict__ sf,
    const float* __restrict__ W2, const float* __restrict__ b2,
    float* __restrict__ out, float* __restrict__ acc)
{
    __shared__ float tile[4][4][64];
    __shared__ float lsum[64], lsq[64];
    const int lane = threadIdx.x & 63;
    const int wv   = threadIdx.x >> 6;
    if (threadIdx.x < 64) { lsum[threadIdx.x] = 0.f; lsq[threadIdx.x] = 0.f; }
    __syncthreads();

    float w[64];
#pragma unroll
    for (int c = 0; c < 64; ++c) w[c] = W2[c * 64 + lane];
    const float bias = b2[lane];
    const float4* __restrict__ sf4 = (const float4*)sf;

    const int gw    = blockIdx.x * 4 + wv;
    const int rbase = gw * RPW;

    float psum = 0.f, psq = 0.f;
#pragma unroll 1
    for (int it = 0; it < RPW / 4; ++it) {
        const int r4 = rbase + it * 4;
        const float4 v = sf4[(size_t)r4 * 16 + lane];   // 4 rows in one load
        ((float4*)&tile[wv][0][0])[lane] = v;
        __builtin_amdgcn_wave_barrier();

        const float4* t0 = (const float4*)&tile[wv][0][0];
        const float4* t1 = (const float4*)&tile[wv][1][0];
        const float4* t2 = (const float4*)&tile[wv][2][0];
        const float4* t3 = (const float4*)&tile[wv][3][0];
        float y0 = bias, y1 = bias, y2 = bias, y3 = bias;
#pragma unroll
        for (int c4 = 0; c4 < 16; ++c4) {
            const float4 p0 = t0[c4], p1 = t1[c4], p2 = t2[c4], p3 = t3[c4];
            const float wa = w[4*c4+0], wb = w[4*c4+1], wc = w[4*c4+2], wd = w[4*c4+3];
            y0 = fmaf(p0.x, wa, y0); y0 = fmaf(p0.y, wb, y0);
            y0 = fmaf(p0.z, wc, y0); y0 = fmaf(p0.w, wd, y0);
            y1 = fmaf(p1.x, wa, y1); y1 = fmaf(p1.y, wb, y1);
            y1 = fmaf(p1.z, wc, y1); y1 = fmaf(p1.w, wd, y1);
            y2 = fmaf(p2.x, wa, y2); y2 = fmaf(p2.y, wb, y2);
            y2 = fmaf(p2.z, wc, y2); y2 = fmaf(p2.w, wd, y2);
            y3 = fmaf(p3.x, wa, y3); y3 = fmaf(p3.y, wb, y3);
            y3 = fmaf(p3.z, wc, y3); y3 = fmaf(p3.w, wd, y3);
        }
        __builtin_amdgcn_wave_barrier();

        out[(size_t)(r4 + 0) * OUTW + 67 + lane] = y0;
        out[(size_t)(r4 + 1) * OUTW + 67 + lane] = y1;
        out[(size_t)(r4 + 2) * OUTW + 67 + lane] = y2;
        out[(size_t)(r4 + 3) * OUTW + 67 + lane] = y3;
        psum += y0 + y1 + y2 + y3;
        psq  += y0*y0 + y1*y1 + y2*y2 + y3*y3;
    }
    atomicAdd(&lsum[lane], psum);
    atomicAdd(&lsq[lane], psq);
    __syncthreads();
    if (threadIdx.x < 64) {
        float* slot = acc + (blockIdx.x & (NSLOT - 1)) * 256;
        atomicAdd(&slot[128 + threadIdx.x], lsum[threadIdx.x]);
        atomicAdd(&slot[192 + threadIdx.x], lsq[threadIdx.x]);
    }
}

// ---------------------------------------------------------------------------
// Finalize (stats folded in): each block folds the NSLOT partial-sum slots
// (16 KB, L2-resident) into a/c in LDS, then applies
//   out[r*131 + 3 + j] = relu(a[j]*y + c[j]),  j in [0,128)
// ---------------------------------------------------------------------------
__global__ __launch_bounds__(256) void k_finalize(
    float* __restrict__ out, const float* __restrict__ ws,
    const float* __restrict__ g1, const float* __restrict__ be1,
    const float* __restrict__ g2, const float* __restrict__ be2)
{
    __shared__ float aN[128], cN[128];
    const int t = threadIdx.x;
    if (t < 64) {
        float s1 = 0.f, q1 = 0.f, s2 = 0.f, q2 = 0.f;
#pragma unroll
        for (int s = 0; s < NSLOT; ++s) {
            const float* p = ws + s * 256;
            s1 += p[t]; q1 += p[64 + t]; s2 += p[128 + t]; q2 += p[192 + t];
        }
        const float inv = 1.0f / (float)ROWS;
        const float m1 = s1 * inv;
        const float a1 = g1[t] * rsqrtf(q1 * inv - m1 * m1 + 1e-5f);
        aN[t] = a1; cN[t] = be1[t] - m1 * a1;
        const float m2 = s2 * inv;
        const float a2 = g2[t] * rsqrtf(q2 * inv - m2 * m2 + 1e-5f);
        aN[64 + t] = a2; cN[64 + t] = be2[t] - m2 * a2;
    }
    __syncthreads();

    const size_t T  = (size_t)gridDim.x * blockDim.x;
    const size_t t0 = (size_t)blockIdx.x * blockDim.x + t;
#pragma unroll
    for (int i = 0; i < 4; ++i) {
        const size_t e = t0 + (size_t)i * T;       // e < ROWS*128
        const size_t r = e >> 7;
        const int    j = (int)(e & 127);
        const size_t ad = r * OUTW + 3 + j;
        const float v = out[ad];
        out[ad] = fmaxf(fmaf(v, aN[j], cN[j]), 0.f);
    }
}

// ---------------------------------------------------------------------------
extern "C" void kernel_launch(void* const* d_in, const int* in_sizes, int n_in,
                              void* d_out, int out_size, void* d_ws, size_t ws_size,
                              hipStream_t stream)
{
    const float* cf     = (const float*)d_in[1];   // curr_feat (B,M,64)
    const float* scoord = (const float*)d_in[2];   // skip_coords (B,N,3)
    const float* sf     = (const float*)d_in[3];   // skip_feat (B,N,64)
    const int*   idxs   = (const int*)  d_in[4];   // upsampling_idxs (B,N,16)
    const float* W1     = (const float*)d_in[5];
    const float* b1     = (const float*)d_in[6];
    const float* g1     = (const float*)d_in[7];
    const float* be1    = (const float*)d_in[8];
    const float* W2     = (const float*)d_in[9];
    const float* b2     = (const float*)d_in[10];
    const float* g2     = (const float*)d_in[11];
    const float* be2    = (const float*)d_in[12];
    float* out = (float*)d_out;
    float* ws  = (float*)d_ws;

    hipMemsetAsync(ws, 0, NSLOT * 256 * sizeof(float), stream);
    k_pool_proj<<<A_BLOCKS, 256, 0, stream>>>(cf, idxs, scoord, W1, b1, out, ws);
    k_skip_proj<<<A_BLOCKS, 256, 0, stream>>>(sf, W2, b2, out, ws);
    // ROWS*128 = 16,777,216 elements; 16384 blocks * 256 threads * 4 elems
    k_finalize<<<16384, 256, 0, stream>>>(out, ws, g1, be1, g2, be2);
}

// Round 6
// 295.952 us; speedup vs baseline: 2.2901x; 1.2302x over previous
//
#include <hip/hip_runtime.h>
#include <hip/hip_bf16.h>

// Problem constants (from reference setup_inputs)
#define BB 4
#define MM 16384
#define NN 32768
#define KK 16
#define ROWS (BB * NN)   // 131072
#define OUTW 131         // 3 coords + 64 + 64
#define RPW 8            // rows per wave (was 32; grid 4x -> occupancy ceiling 100%)
#define A_BLOCKS (ROWS / (RPW * 4))  // 4096 blocks of 4 waves
#define NSLOT 16         // stats accumulator slot copies
#define NEG_INF -3.402823466e38f

// ws layout (floats):
//   [0 : NSLOT*256)  partial sums; slot s at s*256:
//        +0 sum1[64], +64 sq1[64], +128 sum2[64], +192 sq2[64]
//   [4096:4224) a (a1|a2)   [4224:4352) c (c1|c2)

// ---------------------------------------------------------------------------
// Kernel 1: gather + max-pool + (pooled @ W1 + b1) -> out[..., 3:67] (unnorm)
//           + coords -> out[..., 0:3], + per-channel sum/sumsq partials.
// Row body is round-3's proven structure (VGPR 48, 16 gathers in flight,
// FETCH 63 MB). ONLY change: RPW 32->8 so the grid (4096 blocks) no longer
// caps occupancy at 16 waves/CU. Round-5 lesson: any VGPR growth kills this
// kernel; round-4 lesson: >32 gathers in flight/wave thrashes L2.
// ---------------------------------------------------------------------------
__global__ __launch_bounds__(256) void k_pool_proj(
    const float* __restrict__ cf, const int* __restrict__ idxs,
    const float* __restrict__ scoord,
    const float* __restrict__ W1, const float* __restrict__ b1,
    float* __restrict__ out, float* __restrict__ acc)
{
    __shared__ float pool[4][64];
    __shared__ float lsum[64], lsq[64];
    const int lane = threadIdx.x & 63;
    const int wv   = threadIdx.x >> 6;
    if (threadIdx.x < 64) { lsum[threadIdx.x] = 0.f; lsq[threadIdx.x] = 0.f; }
    __syncthreads();

    // XCD-aware decomposition: batch b -> XCD pair {2b, 2b+1}
    // (proven: FETCH 211->66 MB)
    const int xcd   = blockIdx.x & 7;
    const int batch = xcd >> 1;                              // 0..3
    const int blkIB = ((blockIdx.x >> 3) << 1) | (xcd & 1);  // 0..1023
    const int gw    = blkIB * 4 + wv;                        // 0..4095
    const int rbase = (batch << 15) + gw * RPW;
    const float* __restrict__ cfb = cf + ((size_t)batch << 20);  // batch*M*64

    float w[64];
#pragma unroll
    for (int c = 0; c < 64; ++c) w[c] = W1[c * 64 + lane];
    const float bias = b1[lane];

    float psum = 0.f, psq = 0.f;
#pragma unroll 1
    for (int r0 = 0; r0 < RPW; ++r0) {
        const int r = rbase + r0;
        int mi = 0;
        if (lane < KK) mi = idxs[(size_t)r * KK + lane];
        float pmax = NEG_INF;
#pragma unroll
        for (int k = 0; k < KK; ++k) {
            const int m = __shfl(mi, k);
            pmax = fmaxf(pmax, cfb[((size_t)m << 6) + lane]);
        }
        pool[wv][lane] = pmax;                   // wave-private tile
        __builtin_amdgcn_wave_barrier();

        const float4* t4 = (const float4*)(&pool[wv][0]);
        float y = bias;
#pragma unroll
        for (int c4 = 0; c4 < 16; ++c4) {
            const float4 p = t4[c4];
            y = fmaf(p.x, w[c4 * 4 + 0], y);
            y = fmaf(p.y, w[c4 * 4 + 1], y);
            y = fmaf(p.z, w[c4 * 4 + 2], y);
            y = fmaf(p.w, w[c4 * 4 + 3], y);
        }
        __builtin_amdgcn_wave_barrier();

        const size_t ob = (size_t)r * OUTW;
        out[ob + 3 + lane] = y;
        if (lane < 3) out[ob + lane] = scoord[(size_t)r * 3 + lane];
        psum += y; psq += y * y;
    }
    atomicAdd(&lsum[lane], psum);
    atomicAdd(&lsq[lane], psq);
    __syncthreads();
    if (threadIdx.x < 64) {
        float* slot = acc + (blockIdx.x & (NSLOT - 1)) * 256;
        atomicAdd(&slot[threadIdx.x],      lsum[threadIdx.x]);
        atomicAdd(&slot[64 + threadIdx.x], lsq[threadIdx.x]);
    }
}

// ---------------------------------------------------------------------------
// Kernel 2: (skip_feat @ W2 + b2) -> out[..., 67:131] (unnorm) + stats.
// Round-5 4-row float4 body; grid raised to 4096 blocks (RPW=8, 2 iters).
// ---------------------------------------------------------------------------
__global__ __launch_bounds__(256) void k_skip_proj(
    const float* __restrict__ sf,
    const float* __restrict__ W2, const float* __restrict__ b2,
    float* __restrict__ out, float* __restrict__ acc)
{
    __shared__ float tile[4][4][64];
    __shared__ float lsum[64], lsq[64];
    const int lane = threadIdx.x & 63;
    const int wv   = threadIdx.x >> 6;
    if (threadIdx.x < 64) { lsum[threadIdx.x] = 0.f; lsq[threadIdx.x] = 0.f; }
    __syncthreads();

    float w[64];
#pragma unroll
    for (int c = 0; c < 64; ++c) w[c] = W2[c * 64 + lane];
    const float bias = b2[lane];
    const float4* __restrict__ sf4 = (const float4*)sf;

    const int gw    = blockIdx.x * 4 + wv;   // 0..16383
    const int rbase = gw * RPW;

    float psum = 0.f, psq = 0.f;
#pragma unroll 1
    for (int it = 0; it < RPW / 4; ++it) {
        const int r4 = rbase + it * 4;
        const float4 v = sf4[(size_t)r4 * 16 + lane];   // 4 rows in one load
        ((float4*)&tile[wv][0][0])[lane] = v;
        __builtin_amdgcn_wave_barrier();

        const float4* t0 = (const float4*)&tile[wv][0][0];
        const float4* t1 = (const float4*)&tile[wv][1][0];
        const float4* t2 = (const float4*)&tile[wv][2][0];
        const float4* t3 = (const float4*)&tile[wv][3][0];
        float y0 = bias, y1 = bias, y2 = bias, y3 = bias;
#pragma unroll
        for (int c4 = 0; c4 < 16; ++c4) {
            const float4 p0 = t0[c4], p1 = t1[c4], p2 = t2[c4], p3 = t3[c4];
            const float wa = w[4*c4+0], wb = w[4*c4+1], wc = w[4*c4+2], wd = w[4*c4+3];
            y0 = fmaf(p0.x, wa, y0); y0 = fmaf(p0.y, wb, y0);
            y0 = fmaf(p0.z, wc, y0); y0 = fmaf(p0.w, wd, y0);
            y1 = fmaf(p1.x, wa, y1); y1 = fmaf(p1.y, wb, y1);
            y1 = fmaf(p1.z, wc, y1); y1 = fmaf(p1.w, wd, y1);
            y2 = fmaf(p2.x, wa, y2); y2 = fmaf(p2.y, wb, y2);
            y2 = fmaf(p2.z, wc, y2); y2 = fmaf(p2.w, wd, y2);
            y3 = fmaf(p3.x, wa, y3); y3 = fmaf(p3.y, wb, y3);
            y3 = fmaf(p3.z, wc, y3); y3 = fmaf(p3.w, wd, y3);
        }
        __builtin_amdgcn_wave_barrier();

        out[(size_t)(r4 + 0) * OUTW + 67 + lane] = y0;
        out[(size_t)(r4 + 1) * OUTW + 67 + lane] = y1;
        out[(size_t)(r4 + 2) * OUTW + 67 + lane] = y2;
        out[(size_t)(r4 + 3) * OUTW + 67 + lane] = y3;
        psum += y0 + y1 + y2 + y3;
        psq  += y0*y0 + y1*y1 + y2*y2 + y3*y3;
    }
    atomicAdd(&lsum[lane], psum);
    atomicAdd(&lsq[lane], psq);
    __syncthreads();
    if (threadIdx.x < 64) {
        float* slot = acc + (blockIdx.x & (NSLOT - 1)) * 256;
        atomicAdd(&slot[128 + threadIdx.x], lsum[threadIdx.x]);
        atomicAdd(&slot[192 + threadIdx.x], lsq[threadIdx.x]);
    }
}

// ---------------------------------------------------------------------------
// Fold NSLOT partial-sum slots -> a = g*rsqrt(var+eps), c = beta - mu*a.
// One block; finalize reads ws[4096:4352]. (Round-5's per-block fold in
// finalize was pure prologue overhead x 16384 blocks -- reverted.)
// ---------------------------------------------------------------------------
__global__ void k_stats(float* __restrict__ ws,
                        const float* __restrict__ g1, const float* __restrict__ be1,
                        const float* __restrict__ g2, const float* __restrict__ be2)
{
    const int o = threadIdx.x;  // 64 threads
    float s1 = 0.f, q1 = 0.f, s2 = 0.f, q2 = 0.f;
#pragma unroll
    for (int s = 0; s < NSLOT; ++s) {
        const float* p = ws + s * 256;
        s1 += p[o]; q1 += p[64 + o]; s2 += p[128 + o]; q2 += p[192 + o];
    }
    const float inv = 1.0f / (float)ROWS;
    const float m1 = s1 * inv;
    const float a1 = g1[o] * rsqrtf(q1 * inv - m1 * m1 + 1e-5f);
    ws[4096 + o] = a1;
    ws[4224 + o] = be1[o] - m1 * a1;
    const float m2 = s2 * inv;
    const float a2 = g2[o] * rsqrtf(q2 * inv - m2 * m2 + 1e-5f);
    ws[4096 + 64 + o] = a2;
    ws[4224 + 64 + o] = be2[o] - m2 * a2;
}

// ---------------------------------------------------------------------------
// In-place  out[r*131 + 3 + j] = relu(a[j]*y + c[j]),  j in [0,128).
// a/c staged to LDS with a 1-load prologue. 8 elements per thread.
// ---------------------------------------------------------------------------
__global__ __launch_bounds__(256) void k_finalize(float* __restrict__ out,
                                                  const float* __restrict__ ws)
{
    __shared__ float aN[128], cN[128];
    const int t = threadIdx.x;
    if (t < 128)      aN[t] = ws[4096 + t];
    else              cN[t - 128] = ws[4224 + (t - 128)];
    __syncthreads();

    const size_t T  = (size_t)gridDim.x * blockDim.x;
    const size_t t0 = (size_t)blockIdx.x * blockDim.x + t;
#pragma unroll
    for (int i = 0; i < 8; ++i) {
        const size_t e = t0 + (size_t)i * T;       // e < ROWS*128
        const size_t r = e >> 7;
        const int    j = (int)(e & 127);
        const size_t ad = r * OUTW + 3 + j;
        const float v = out[ad];
        out[ad] = fmaxf(fmaf(v, aN[j], cN[j]), 0.f);
    }
}

// ---------------------------------------------------------------------------
extern "C" void kernel_launch(void* const* d_in, const int* in_sizes, int n_in,
                              void* d_out, int out_size, void* d_ws, size_t ws_size,
                              hipStream_t stream)
{
    const float* cf     = (const float*)d_in[1];   // curr_feat (B,M,64)
    const float* scoord = (const float*)d_in[2];   // skip_coords (B,N,3)
    const float* sf     = (const float*)d_in[3];   // skip_feat (B,N,64)
    const int*   idxs   = (const int*)  d_in[4];   // upsampling_idxs (B,N,16)
    const float* W1     = (const float*)d_in[5];
    const float* b1     = (const float*)d_in[6];
    const float* g1     = (const float*)d_in[7];
    const float* be1    = (const float*)d_in[8];
    const float* W2     = (const float*)d_in[9];
    const float* b2     = (const float*)d_in[10];
    const float* g2     = (const float*)d_in[11];
    const float* be2    = (const float*)d_in[12];
    float* out = (float*)d_out;
    float* ws  = (float*)d_ws;

    hipMemsetAsync(ws, 0, NSLOT * 256 * sizeof(float), stream);
    k_pool_proj<<<A_BLOCKS, 256, 0, stream>>>(cf, idxs, scoord, W1, b1, out, ws);
    k_skip_proj<<<A_BLOCKS, 256, 0, stream>>>(sf, W2, b2, out, ws);
    k_stats<<<1, 64, 0, stream>>>(ws, g1, be1, g2, be2);
    // ROWS*128 = 16,777,216 elements; 8192 blocks * 256 threads * 8 elems
    k_finalize<<<8192, 256, 0, stream>>>(out, ws);
}